// Round 1
// baseline (190.081 us; speedup 1.0000x reference)
//
#include <hip/hip_runtime.h>

// EncoderDecoderLSTM fused kernel for MI355X (gfx950).
//
// Math: state never updates, h0=c0=0  =>
//   gates = input @ (W_ih @ enc_W)^T + (W_ih @ enc_b + b_ih + b_hh)
//   f-gate is dead (multiplies c0=0). Only i,g,o needed (768 of 1024 rows).
//   h = sigmoid(o) * tanh( sigmoid(i) * tanh(g) )
//   out = h @ dec_W^T + dec_b
//
// prep_kernel: fuse weights -> Mb f16[768][32], fb f32[768], decWb f16[32][256]
// lstm_main:   per-wave 32 rows (2x16), f16 MFMA 16x16x32 gates + decoder,
//              LDS round-trip for C-layout -> B-operand-layout transform.

typedef _Float16 f16x8 __attribute__((ext_vector_type(8)));
typedef float    f32x4 __attribute__((ext_vector_type(4)));

#define T_IN 2048
#define TT   2112   // T + future_n
#define FIN  32
#define HID  256
#define FOUT 32

// ws layout (bytes): Mb @0 (49152), fb @49152 (3072), decWb @52224 (16384)
#define WS_FB_OFF   49152
#define WS_DECW_OFF 52224

__device__ __forceinline__ float fsigmoid(float x) {
    x = fminf(fmaxf(x, -30.f), 30.f);
    float e = __builtin_amdgcn_exp2f(-1.4426950408889634f * x);
    return __builtin_amdgcn_rcpf(1.0f + e);
}
__device__ __forceinline__ float ftanh(float x) {
    x = fminf(fmaxf(x, -15.f), 15.f);
    float e = __builtin_amdgcn_exp2f(2.8853900817779268f * x);  // e^(2x)
    return (e - 1.0f) * __builtin_amdgcn_rcpf(e + 1.0f);
}

__global__ void prep_kernel(const float* __restrict__ enc_W, const float* __restrict__ enc_b,
                            const float* __restrict__ W_ih, const float* __restrict__ b_ih,
                            const float* __restrict__ b_hh, const float* __restrict__ dec_W,
                            _Float16* __restrict__ Mb, float* __restrict__ fb,
                            _Float16* __restrict__ decWb) {
    int tid = blockIdx.x * 256 + threadIdx.x;
    if (tid < 24576) {
        // M[gg][f] = sum_r W_ih[sg][r] * enc_W[r][f];  gg: 0-255=i, 256-511=g, 512-767=o
        int f = tid & 31, gg = tid >> 5;
        int sg = gg + (gg >= 256 ? 256 : 0);  // skip dead f-gate rows 256..511
        const float* wr = W_ih + (size_t)sg * 256;
        float acc = 0.f;
#pragma unroll 8
        for (int r = 0; r < 256; ++r) acc += wr[r] * enc_W[r * 32 + f];
        Mb[tid] = (_Float16)acc;
    } else if (tid < 24576 + 768) {
        int gg = tid - 24576;
        int sg = gg + (gg >= 256 ? 256 : 0);
        const float* wr = W_ih + (size_t)sg * 256;
        float acc = b_ih[sg] + b_hh[sg];
#pragma unroll 8
        for (int r = 0; r < 256; ++r) acc += wr[r] * enc_b[r];
        fb[gg] = acc;
    } else if (tid < 24576 + 768 + 8192) {
        int i = tid - (24576 + 768);
        decWb[i] = (_Float16)dec_W[i];
    }
}

__global__ __launch_bounds__(256) void lstm_main(
    const float* __restrict__ in, const _Float16* __restrict__ Mb,
    const float* __restrict__ fb, const _Float16* __restrict__ decWb,
    const float* __restrict__ dec_b, float* __restrict__ out) {
    // per-wave LDS: h tile [16 t][40 f16] (pitch 40 -> 2-way bank alias = free)
    __shared__ _Float16 hbuf[4][2][16 * 40];

    const int lane = threadIdx.x & 63;
    const int w    = threadIdx.x >> 6;
    const int l16  = lane & 15;
    const int q    = lane >> 4;
    const int wave = blockIdx.x * 4 + w;
    const int rowbase = wave * 32;            // 2112 % 32 == 0: one b per wave
    const int b  = rowbase / TT;
    const int t0 = rowbase - b * TT;

    // Input B-fragments: B[k=q*8+j][n=l16] = input[b][min(t,2047)][q*8+j]
    f16x8 bfr[2];
#pragma unroll
    for (int s = 0; s < 2; ++s) {
        int t  = t0 + s * 16 + l16;
        int tr = t < T_IN ? t : (T_IN - 1);
        const float* p = in + ((size_t)(b * T_IN + tr)) * FIN + q * 8;
        f32x4 u0 = *(const f32x4*)(p);
        f32x4 u1 = *(const f32x4*)(p + 4);
        f16x8 v;
#pragma unroll
        for (int j = 0; j < 4; ++j) { v[j] = (_Float16)u0[j]; v[4 + j] = (_Float16)u1[j]; }
        bfr[s] = v;
    }

    const f32x4 zero = {0.f, 0.f, 0.f, 0.f};
    f32x4 dacc[2][2] = {{zero, zero}, {zero, zero}};

    for (int hc = 0; hc < 8; ++hc) {
        const int hb = hc * 32;
        // Gate weight A-frags: A[m=l16][k=q*8+j] = Mb[gt*256 + hb + X*16 + l16][k]
        f16x8 afr[3][2];
        f32x4 fbv[3][2];
#pragma unroll
        for (int gt = 0; gt < 3; ++gt)
#pragma unroll
            for (int X = 0; X < 2; ++X) {
                int grow = gt * 256 + hb + X * 16;
                afr[gt][X] = *(const f16x8*)(Mb + (size_t)(grow + l16) * 32 + q * 8);
                fbv[gt][X] = *(const f32x4*)(fb + grow + q * 4);
            }
        // Decoder A-frags: A2[m=l16 -> od=ot*16+l16][k=q*8+j -> hid=hb+k]
        f16x8 a2[2];
#pragma unroll
        for (int ot = 0; ot < 2; ++ot)
            a2[ot] = *(const f16x8*)(decWb + (size_t)(ot * 16 + l16) * 256 + hb + q * 8);

#pragma unroll
        for (int s = 0; s < 2; ++s) {
            // D[gate 4q+r][t=l16] for gate subtiles X (16 hid each), types i,g,o
            f32x4 gi[2], gg[2], go[2];
#pragma unroll
            for (int X = 0; X < 2; ++X) {
                gi[X] = __builtin_amdgcn_mfma_f32_16x16x32_f16(afr[0][X], bfr[s], zero, 0, 0, 0);
                gg[X] = __builtin_amdgcn_mfma_f32_16x16x32_f16(afr[1][X], bfr[s], zero, 0, 0, 0);
                go[X] = __builtin_amdgcn_mfma_f32_16x16x32_f16(afr[2][X], bfr[s], zero, 0, 0, 0);
            }
            _Float16* hp = &hbuf[w][s][0];
#pragma unroll
            for (int X = 0; X < 2; ++X)
#pragma unroll
                for (int r = 0; r < 4; ++r) {
                    float iv = gi[X][r] + fbv[0][X][r];
                    float gv = gg[X][r] + fbv[1][X][r];
                    float ov = go[X][r] + fbv[2][X][r];
                    float c  = fsigmoid(iv) * ftanh(gv);
                    float hv = fsigmoid(ov) * ftanh(c);
                    // h[t=l16][hidlocal = X*16 + 4q + r]
                    hp[l16 * 40 + X * 16 + q * 4 + r] = (_Float16)hv;
                }
            // wave-internal cross-lane LDS handoff: drain DS queue, block reordering
            asm volatile("s_waitcnt lgkmcnt(0)" ::: "memory");
            // B2[k=q*8+j][n=l16] = h[t=l16][hb + q*8+j]
            f16x8 b2 = *(const f16x8*)(hp + l16 * 40 + q * 8);
#pragma unroll
            for (int ot = 0; ot < 2; ++ot)
                dacc[s][ot] = __builtin_amdgcn_mfma_f32_16x16x32_f16(a2[ot], b2, dacc[s][ot], 0, 0, 0);
        }
    }

    // D2[od = ot*16 + 4q + r][t=l16] -> out[(b*TT+t)*32 + od], float4 per lane
#pragma unroll
    for (int s = 0; s < 2; ++s) {
        int t = t0 + s * 16 + l16;
        size_t ro = ((size_t)(b * TT + t)) * FOUT;
#pragma unroll
        for (int ot = 0; ot < 2; ++ot) {
            f32x4 v  = dacc[s][ot];
            f32x4 db = *(const f32x4*)(dec_b + ot * 16 + q * 4);
            v = v + db;
            *(f32x4*)(out + ro + ot * 16 + q * 4) = v;
        }
    }
}

extern "C" void kernel_launch(void* const* d_in, const int* in_sizes, int n_in,
                              void* d_out, int out_size, void* d_ws, size_t ws_size,
                              hipStream_t stream) {
    const float* input = (const float*)d_in[0];
    const float* enc_W = (const float*)d_in[1];
    const float* enc_b = (const float*)d_in[2];
    const float* W_ih  = (const float*)d_in[3];
    // d_in[4] = W_hh: unused (h0 = 0 -> state_gates = b_hh only)
    const float* b_ih  = (const float*)d_in[5];
    const float* b_hh  = (const float*)d_in[6];
    const float* dec_W = (const float*)d_in[7];
    const float* dec_b = (const float*)d_in[8];
    // d_in[9] = future_n (fixed 64, baked into TT)

    _Float16* Mb    = (_Float16*)d_ws;
    float*    fb    = (float*)((char*)d_ws + WS_FB_OFF);
    _Float16* decWb = (_Float16*)((char*)d_ws + WS_DECW_OFF);
    float*    out   = (float*)d_out;

    prep_kernel<<<132, 256, 0, stream>>>(enc_W, enc_b, W_ih, b_ih, b_hh, dec_W, Mb, fb, decWb);
    // 128 b * 2112 t rows / 32 rows-per-wave = 8448 waves; 4 waves/block
    lstm_main<<<2112, 256, 0, stream>>>(input, Mb, fb, decWb, dec_b, out);
}

// Round 2
// 169.248 us; speedup vs baseline: 1.1231x; 1.1231x over previous
//
#include <hip/hip_runtime.h>

// EncoderDecoderLSTM fused kernel for MI355X (gfx950).
//
// Math: state never updates, h0=c0=0  =>
//   gates = input @ (W_ih @ enc_W)^T + (W_ih @ enc_b + b_ih + b_hh)
//   f-gate is dead (multiplies c0=0). Only i,g,o needed (768 of 1024 rows).
//   c = sigmoid(i)*tanh(g) = (E-1)/((1+U)(1+E)),  U=e^-i, E=e^2g
//   h = sigmoid(o) * tanhpoly(c)      (|c|<1 -> degree-11 odd poly, no trans)
//   out = h @ dec_W^T + dec_b
//
// prep2: block-per-row parallel weight fusion (768 rows, 32-iter loops).
// lstm_main: per-wave 32 rows, f16 MFMA 16x16x32; biases ride the MFMA C
//   operand; h packed via cvt_pkrtz -> 8B LDS writes; decoder MFMA from LDS.

typedef _Float16 f16x8 __attribute__((ext_vector_type(8)));
typedef _Float16 f16x4 __attribute__((ext_vector_type(4)));
typedef float    f32x4 __attribute__((ext_vector_type(4)));
typedef __fp16   h16x2 __attribute__((ext_vector_type(2)));

#define T_IN 2048
#define TT   2112   // T + future_n
#define FIN  32
#define FOUT 32

// ws layout (bytes): Mb @0 (49152), fb @49152 (3072), decWb @52224 (16384)
#define WS_FB_OFF   49152
#define WS_DECW_OFF 52224

union PkU { h16x2 h; unsigned u; };

__global__ __launch_bounds__(256) void prep2(
    const float* __restrict__ enc_W, const float* __restrict__ enc_b,
    const float* __restrict__ W_ih, const float* __restrict__ b_ih,
    const float* __restrict__ b_hh, const float* __restrict__ dec_W,
    _Float16* __restrict__ Mb, float* __restrict__ fb, _Float16* __restrict__ decWb) {
    const int blk = blockIdx.x;
    const int tid = threadIdx.x;
    if (blk < 768) {
        // row gg: 0-255 = i (sg=gg), 256-511 = g (sg=gg+256), 512-767 = o
        const int gg = blk, sg = gg + (gg >= 256 ? 256 : 0);
        const float* wr = W_ih + (size_t)sg * 256;
        const int f = tid & 31, r8 = tid >> 5;
        float acc = 0.f;
#pragma unroll
        for (int k = 0; k < 32; ++k) {
            int r = r8 * 32 + k;
            acc = fmaf(wr[r], enc_W[r * 32 + f], acc);
        }
        __shared__ float red[256];
        __shared__ float redb[256];
        __shared__ float red2[32];
        red[tid]  = acc;
        redb[tid] = wr[tid] * enc_b[tid];
        __syncthreads();
        if (tid < 32) {
            float s = 0.f;
#pragma unroll
            for (int k = 0; k < 8; ++k) s += red[k * 32 + tid];
            Mb[gg * 32 + tid] = (_Float16)s;
        } else if (tid >= 128 && tid < 160) {
            int t2 = tid - 128;
            float s2 = 0.f;
#pragma unroll
            for (int k = 0; k < 8; ++k) s2 += redb[t2 * 8 + k];
            red2[t2] = s2;
        }
        __syncthreads();
        if (tid == 0) {
            float t = b_ih[sg] + b_hh[sg];
#pragma unroll
            for (int k = 0; k < 32; ++k) t += red2[k];
            fb[gg] = t;
        }
    } else {
        // blocks 768..775: dec_W f32 -> f16 (8192 elems, 4/thread)
        int i = (blk - 768) * 1024 + tid * 4;
        f32x4 v = *(const f32x4*)(dec_W + i);
        f16x4 o;
#pragma unroll
        for (int j = 0; j < 4; ++j) o[j] = (_Float16)v[j];
        *(f16x4*)(decWb + i) = o;
    }
}

__global__ __launch_bounds__(256) void lstm_main(
    const float* __restrict__ in, const _Float16* __restrict__ Mb,
    const float* __restrict__ fb, const _Float16* __restrict__ decWb,
    const float* __restrict__ dec_b, float* __restrict__ out) {
    // per-wave LDS: h tile [16 t][40 f16] (pitch 40 -> 2-way bank alias = free)
    __shared__ _Float16 hbuf[4][2][16 * 40];

    const int lane = threadIdx.x & 63;
    const int w    = threadIdx.x >> 6;
    const int l16  = lane & 15;
    const int q    = lane >> 4;
    const int wave = blockIdx.x * 4 + w;
    const int rowbase = wave * 32;            // 2112 % 32 == 0: one b per wave
    const int b  = rowbase / TT;
    const int t0 = rowbase - b * TT;

    // Input B-fragments: B[k=q*8+j][n=l16] = input[b][min(t,2047)][q*8+j]
    f16x8 bfr[2];
#pragma unroll
    for (int s = 0; s < 2; ++s) {
        int t  = t0 + s * 16 + l16;
        int tr = t < T_IN ? t : (T_IN - 1);
        const float* p = in + ((size_t)(b * T_IN + tr)) * FIN + q * 8;
        f32x4 u0 = *(const f32x4*)(p);
        f32x4 u1 = *(const f32x4*)(p + 4);
        f16x8 v;
#pragma unroll
        for (int j = 0; j < 4; ++j) { v[j] = (_Float16)u0[j]; v[4 + j] = (_Float16)u1[j]; }
        bfr[s] = v;
    }

    // decoder acc starts at dec_b (rides the MFMA C operand)
    f32x4 dacc[2][2];
#pragma unroll
    for (int ot = 0; ot < 2; ++ot) {
        f32x4 db = *(const f32x4*)(dec_b + ot * 16 + q * 4);
        dacc[0][ot] = db; dacc[1][ot] = db;
    }

    for (int hc = 0; hc < 8; ++hc) {
        const int hb = hc * 32;
        // Gate weight A-frags + bias C-frags
        f16x8 afr[3][2];
        f32x4 fbv[3][2];
#pragma unroll
        for (int gt = 0; gt < 3; ++gt)
#pragma unroll
            for (int X = 0; X < 2; ++X) {
                int grow = gt * 256 + hb + X * 16;
                afr[gt][X] = *(const f16x8*)(Mb + (size_t)(grow + l16) * 32 + q * 8);
                fbv[gt][X] = *(const f32x4*)(fb + grow + q * 4);
            }
        // Decoder A-frags: A2[m=ot*16+l16][k -> hid=hb+q*8+j]
        f16x8 a2[2];
#pragma unroll
        for (int ot = 0; ot < 2; ++ot)
            a2[ot] = *(const f16x8*)(decWb + (size_t)(ot * 16 + l16) * 256 + hb + q * 8);

#pragma unroll
        for (int s = 0; s < 2; ++s) {
            // D[m = gate hid][n = t]; bias pre-loaded as C operand
            f32x4 gi[2], gg[2], go[2];
#pragma unroll
            for (int X = 0; X < 2; ++X) {
                gi[X] = __builtin_amdgcn_mfma_f32_16x16x32_f16(afr[0][X], bfr[s], fbv[0][X], 0, 0, 0);
                gg[X] = __builtin_amdgcn_mfma_f32_16x16x32_f16(afr[1][X], bfr[s], fbv[1][X], 0, 0, 0);
                go[X] = __builtin_amdgcn_mfma_f32_16x16x32_f16(afr[2][X], bfr[s], fbv[2][X], 0, 0, 0);
            }
            _Float16* hp = &hbuf[w][s][0];
#pragma unroll
            for (int X = 0; X < 2; ++X) {
                float hv[4];
#pragma unroll
                for (int r = 0; r < 4; ++r) {
                    float iv = gi[X][r], gv = gg[X][r], ov = go[X][r];
                    // c = sigmoid(i)*tanh(g) = (E-1)/((1+U)(1+E)); saturations
                    // resolve via rcp(inf)=0; single clamp keeps E finite.
                    float U  = __builtin_amdgcn_exp2f(-1.4426950408889634f * iv);
                    float gc = fminf(gv, 30.f);
                    float E  = __builtin_amdgcn_exp2f(2.8853900817779268f * gc);
                    float c  = (E - 1.0f) * __builtin_amdgcn_rcpf((1.0f + U) * (1.0f + E));
                    // tanh(c), |c|<1: odd Cephes poly, no trans ops
                    float z  = c * c;
                    float P  = fmaf(z, fmaf(z, fmaf(z, fmaf(z, -5.70498872745e-3f,
                                    2.06390887954e-2f), -5.37397155531e-2f),
                                    1.33314422036e-1f), -3.33332819422e-1f);
                    float tc = fmaf(c * z, P, c);
                    float Uo = __builtin_amdgcn_exp2f(-1.4426950408889634f * ov);
                    float so = __builtin_amdgcn_rcpf(1.0f + Uo);
                    hv[r] = so * tc;
                }
                // pack 4 f16 -> one 8B LDS write: h[t=l16][X*16 + q*4 + r]
                PkU p0, p1;
                p0.h = __builtin_amdgcn_cvt_pkrtz(hv[0], hv[1]);
                p1.h = __builtin_amdgcn_cvt_pkrtz(hv[2], hv[3]);
                uint2 wv = { p0.u, p1.u };
                *(uint2*)(hp + l16 * 40 + X * 16 + q * 4) = wv;
            }
            // wave-internal cross-lane LDS handoff
            asm volatile("s_waitcnt lgkmcnt(0)" ::: "memory");
            // B2[k=q*8+j][n=l16] = h[t=l16][hb + q*8+j]
            f16x8 b2 = *(const f16x8*)(hp + l16 * 40 + q * 8);
#pragma unroll
            for (int ot = 0; ot < 2; ++ot)
                dacc[s][ot] = __builtin_amdgcn_mfma_f32_16x16x32_f16(a2[ot], b2, dacc[s][ot], 0, 0, 0);
        }
    }

    // D2[od = ot*16 + 4q + r][t=l16] -> out[(b*TT+t)*32 + od], float4 per lane
#pragma unroll
    for (int s = 0; s < 2; ++s) {
        int t = t0 + s * 16 + l16;
        size_t ro = ((size_t)(b * TT + t)) * FOUT;
#pragma unroll
        for (int ot = 0; ot < 2; ++ot)
            *(f32x4*)(out + ro + ot * 16 + q * 4) = dacc[s][ot];
    }
}

extern "C" void kernel_launch(void* const* d_in, const int* in_sizes, int n_in,
                              void* d_out, int out_size, void* d_ws, size_t ws_size,
                              hipStream_t stream) {
    const float* input = (const float*)d_in[0];
    const float* enc_W = (const float*)d_in[1];
    const float* enc_b = (const float*)d_in[2];
    const float* W_ih  = (const float*)d_in[3];
    // d_in[4] = W_hh: unused (h0 = 0 -> state_gates = b_hh only)
    const float* b_ih  = (const float*)d_in[5];
    const float* b_hh  = (const float*)d_in[6];
    const float* dec_W = (const float*)d_in[7];
    const float* dec_b = (const float*)d_in[8];
    // d_in[9] = future_n (fixed 64, baked into TT)

    _Float16* Mb    = (_Float16*)d_ws;
    float*    fb    = (float*)((char*)d_ws + WS_FB_OFF);
    _Float16* decWb = (_Float16*)((char*)d_ws + WS_DECW_OFF);
    float*    out   = (float*)d_out;

    prep2<<<776, 256, 0, stream>>>(enc_W, enc_b, W_ih, b_ih, b_hh, dec_W, Mb, fb, decWb);
    // 128 b * 2112 t rows / 32 rows-per-wave = 8448 waves; 4 waves/block
    lstm_main<<<2112, 256, 0, stream>>>(input, Mb, fb, decWb, dec_b, out);
}